// Round 1
// baseline (206.649 us; speedup 1.0000x reference)
//
#include <hip/hip_runtime.h>
#include <math.h>

#define K_NB   32
#define C_IN   64
#define C_OUT  128
#define NPART  256   // partial-sum blocks for batchnorm stats

// ---------------------------------------------------------------------------
// K1: fused  n_p = p[idx];  pooled = max_k [p[knn]-n_p , x[knn]];  h = pooled@W + b
// One wave (64 lanes) per sampled point. 4 waves / block.
// h is written pre-BN into the x_out region of d_out (normalized in-place later).
// ---------------------------------------------------------------------------
__global__ __launch_bounds__(256) void sa_fuse(
    const float* __restrict__ p, const float* __restrict__ x,
    const int* __restrict__ idx, const int* __restrict__ knn,
    const float* __restrict__ W, const float* __restrict__ bias,
    float* __restrict__ np_out, float* __restrict__ h_out)
{
    const int lane = threadIdx.x & 63;
    const int wid  = threadIdx.x >> 6;
    const int m    = blockIdx.x * 4 + wid;

    // neighbor indices: lanes 0..31 hold one each (coalesced 128B load)
    int kidx = 0;
    if (lane < K_NB) kidx = knn[m * K_NB + lane];

    // ---- feature max-pool: lane = channel, broadcast index per k ----
    float xmax = -INFINITY;
    #pragma unroll
    for (int k = 0; k < K_NB; ++k) {
        int nb = __shfl(kidx, k);                 // wave-uniform neighbor id
        xmax = fmaxf(xmax, x[(size_t)nb * C_IN + lane]);  // coalesced 256B row
    }

    // ---- xyz max-pool: lanes 0..31 load their neighbor's xyz, butterfly max ----
    float px = -INFINITY, py = -INFINITY, pz = -INFINITY;
    if (lane < K_NB) {
        const float* pp = p + (size_t)kidx * 3;
        px = pp[0]; py = pp[1]; pz = pp[2];
    }
    #pragma unroll
    for (int off = 32; off >= 1; off >>= 1) {
        px = fmaxf(px, __shfl_xor(px, off));
        py = fmaxf(py, __shfl_xor(py, off));
        pz = fmaxf(pz, __shfl_xor(pz, off));
    }

    // ---- center point (wave-uniform, same-address broadcast load) ----
    const int s = idx[m];
    const float npx = p[(size_t)s*3+0];
    const float npy = p[(size_t)s*3+1];
    const float npz = p[(size_t)s*3+2];
    if (lane < 3) np_out[(size_t)m*3 + lane] = (lane == 0) ? npx : (lane == 1 ? npy : npz);

    // max_k (p[knn]-n_p) = (max_k p[knn]) - n_p  (n_p constant over k)
    const float r0 = px - npx, r1 = py - npy, r2 = pz - npz;

    // ---- Linear(67->128): each lane computes channels {lane, lane+64} ----
    float acc0 = bias[lane], acc1 = bias[64 + lane];
    acc0 = fmaf(r0, W[0*C_OUT +      lane], acc0);
    acc1 = fmaf(r0, W[0*C_OUT + 64 + lane], acc1);
    acc0 = fmaf(r1, W[1*C_OUT +      lane], acc0);
    acc1 = fmaf(r1, W[1*C_OUT + 64 + lane], acc1);
    acc0 = fmaf(r2, W[2*C_OUT +      lane], acc0);
    acc1 = fmaf(r2, W[2*C_OUT + 64 + lane], acc1);
    #pragma unroll
    for (int c = 0; c < C_IN; ++c) {
        float a = __shfl(xmax, c);                // broadcast pooled channel c
        acc0 = fmaf(a, W[(3+c)*C_OUT +      lane], acc0);  // coalesced, L1-resident
        acc1 = fmaf(a, W[(3+c)*C_OUT + 64 + lane], acc1);
    }
    h_out[(size_t)m*C_OUT +      lane] = acc0;
    h_out[(size_t)m*C_OUT + 64 + lane] = acc1;
}

// ---------------------------------------------------------------------------
// K2: per-block partial column sums/sumsqs of h  ->  part[b][0..127]=sum, [128..255]=sumsq
// ---------------------------------------------------------------------------
__global__ __launch_bounds__(128) void sa_colsum(
    const float* __restrict__ h, float* __restrict__ part, int M)
{
    const int j = threadIdx.x;         // channel
    const int b = blockIdx.x;          // NPART blocks
    float s = 0.f, s2 = 0.f;
    for (int m = b; m < M; m += NPART) {
        float v = h[(size_t)m * C_OUT + j];
        s += v;
        s2 = fmaf(v, v, s2);
    }
    part[(size_t)b * 2 * C_OUT + j]         = s;
    part[(size_t)b * 2 * C_OUT + C_OUT + j] = s2;
}

// ---------------------------------------------------------------------------
// K3: reduce partials -> scale/shift per channel; also writes n_o
// ---------------------------------------------------------------------------
__global__ __launch_bounds__(128) void sa_finalize(
    const float* __restrict__ part, const float* __restrict__ gamma,
    const float* __restrict__ beta, float* __restrict__ ss,
    float* __restrict__ no_out, int M)
{
    const int j = threadIdx.x;
    float s = 0.f, s2 = 0.f;
    for (int b = 0; b < NPART; ++b) {
        s  += part[(size_t)b * 2 * C_OUT + j];
        s2 += part[(size_t)b * 2 * C_OUT + C_OUT + j];
    }
    const float inv_m = 1.0f / (float)M;
    const float mean = s * inv_m;
    const float var  = fmaf(-mean, mean, s2 * inv_m);
    const float sc   = gamma[j] * rsqrtf(var + 1e-5f);
    ss[j]          = sc;
    ss[C_OUT + j]  = fmaf(-mean, sc, beta[j]);
    if (j == 0) no_out[0] = (float)M;    // n_o = [M]
}

// ---------------------------------------------------------------------------
// K4: in-place affine + ReLU over h (float4 vectorized)
// ---------------------------------------------------------------------------
__global__ __launch_bounds__(256) void sa_bnrelu(
    float* __restrict__ h, const float* __restrict__ ss, int M)
{
    __shared__ float sc[C_OUT], sh[C_OUT];
    if (threadIdx.x < C_OUT) {
        sc[threadIdx.x] = ss[threadIdx.x];
        sh[threadIdx.x] = ss[C_OUT + threadIdx.x];
    }
    __syncthreads();
    const size_t total4 = (size_t)M * C_OUT / 4;
    float4* h4 = (float4*)h;
    for (size_t i = (size_t)blockIdx.x * blockDim.x + threadIdx.x;
         i < total4; i += (size_t)gridDim.x * blockDim.x) {
        float4 v = h4[i];
        const int c = (int)((i * 4) & (C_OUT - 1));
        v.x = fmaxf(fmaf(v.x, sc[c+0], sh[c+0]), 0.f);
        v.y = fmaxf(fmaf(v.y, sc[c+1], sh[c+1]), 0.f);
        v.z = fmaxf(fmaf(v.z, sc[c+2], sh[c+2]), 0.f);
        v.w = fmaxf(fmaf(v.w, sc[c+3], sh[c+3]), 0.f);
        h4[i] = v;
    }
}

extern "C" void kernel_launch(void* const* d_in, const int* in_sizes, int n_in,
                              void* d_out, int out_size, void* d_ws, size_t ws_size,
                              hipStream_t stream)
{
    const float* p     = (const float*)d_in[0];
    const float* x     = (const float*)d_in[1];
    // d_in[2] = o (unused)
    const int*   idx   = (const int*)d_in[3];
    const int*   knn   = (const int*)d_in[4];
    const float* W     = (const float*)d_in[5];
    const float* bias  = (const float*)d_in[6];
    const float* gamma = (const float*)d_in[7];
    const float* beta  = (const float*)d_in[8];

    const int M = in_sizes[3];   // 65536

    float* out    = (float*)d_out;
    float* np_out = out;                                   // [M,3]
    float* h      = out + (size_t)M * 3;                   // [M,128] (pre-BN, in-place)
    float* no_out = out + (size_t)M * 3 + (size_t)M * C_OUT; // [1]

    float* part = (float*)d_ws;                 // NPART * 256 floats
    float* ss   = part + (size_t)NPART * 2 * C_OUT; // 256 floats (scale|shift)

    sa_fuse    <<<M / 4, 256, 0, stream>>>(p, x, idx, knn, W, bias, np_out, h);
    sa_colsum  <<<NPART, 128, 0, stream>>>(h, part, M);
    sa_finalize<<<1,     128, 0, stream>>>(part, gamma, beta, ss, no_out, M);
    sa_bnrelu  <<<2048,  256, 0, stream>>>(h, ss, M);
}